// Round 1
// baseline (1089.754 us; speedup 1.0000x reference)
//
#include <hip/hip_runtime.h>

#define NX   262144      // 512*512
#define VSZ  65536       // 128*512
#define SSZ  33554432    // 128*512*512

// ---------------------------------------------------------------------------
// Kernel 1: register-resident Gauss-Jordan inversion of three 128x128 matrices.
// 3 blocks x 1024 threads. Thread t owns row r = t>>3, columns [ch*32, ch*32+32)
// of the augmented [G | I] (256 columns) in 32 registers. No pivoting:
// G = I + E with spectral radius(E) < 0.6 -> all leading minors nonsingular.
// Writes inv(G) TRANSPOSED (GinvT[j][i] = Ginv[i][j]) to ws, per matrix.
// ---------------------------------------------------------------------------
__global__ __launch_bounds__(1024)
void invert_gj(const float* __restrict__ g0, const float* __restrict__ g1,
               const float* __restrict__ g2, float* __restrict__ ginvT) {
    const int b = blockIdx.x;
    const float* G = (b == 0) ? g0 : ((b == 1) ? g1 : g2);
    const int t  = threadIdx.x;
    const int r  = t >> 3;        // row 0..127
    const int ch = t & 7;         // column chunk 0..7
    const int cb = ch << 5;       // chunk base column 0..224

    float a[32];
    if (ch < 4) {                 // left half: G
        const float4* gp = (const float4*)(G + r * 128 + cb);
        #pragma unroll
        for (int q = 0; q < 8; ++q) {
            float4 tv = gp[q];
            a[4*q+0] = tv.x; a[4*q+1] = tv.y; a[4*q+2] = tv.z; a[4*q+3] = tv.w;
        }
    } else {                      // right half: I
        #pragma unroll
        for (int j = 0; j < 32; ++j) a[j] = (cb + j - 128 == r) ? 1.0f : 0.0f;
    }

    __shared__ float colk[128];
    __shared__ float rowk[256];

    for (int k = 0; k < 128; ++k) {
        const int kch = k >> 5, kj = k & 31;
        if (ch == kch) {
            // static-index select of a[kj] (register array must not be
            // dynamically indexed -> cndmask chain)
            float sel = a[0];
            #pragma unroll
            for (int j = 1; j < 32; ++j) if (j == kj) sel = a[j];
            colk[r] = sel;
        }
        __syncthreads();
        const float pinv = 1.0f / colk[k];
        if (r == k) {             // normalize pivot row, publish it
            #pragma unroll
            for (int j = 0; j < 32; ++j) { a[j] *= pinv; rowk[cb + j] = a[j]; }
        }
        __syncthreads();
        if (r != k) {             // rank-1 elimination, all 256 columns
            const float fac = colk[r];
            #pragma unroll
            for (int j = 0; j < 32; ++j) a[j] = fmaf(-fac, rowk[cb + j], a[j]);
        }
        __syncthreads();          // protect colk/rowk for next step
    }

    if (ch >= 4) {                // right half now holds Ginv; store transposed
        float* dst = ginvT + b * 16384;
        #pragma unroll
        for (int j = 0; j < 32; ++j) dst[(cb - 128 + j) * 128 + r] = a[j];
    }
}

// ---------------------------------------------------------------------------
// Kernel 2: vn[i,n] = sum_j g[j,i] * v[j,n]   (g^T @ v), 128x512 per tensor.
// Block-uniform i -> g reads become scalar loads; v reads coalesced.
// ---------------------------------------------------------------------------
__global__ __launch_bounds__(256)
void vt_kernel(const float* __restrict__ g0, const float* __restrict__ g1,
               const float* __restrict__ g2, const float* __restrict__ v0,
               const float* __restrict__ v1, const float* __restrict__ v2,
               float* __restrict__ out) {
    const int b = blockIdx.y;
    const float* G = (b == 0) ? g0 : ((b == 1) ? g1 : g2);
    const float* V = (b == 0) ? v0 : ((b == 1) ? v1 : v2);
    const int i = blockIdx.x >> 1;                           // uniform per block
    const int n = ((blockIdx.x & 1) << 8) | threadIdx.x;     // 0..511
    float acc = 0.0f;
    #pragma unroll 8
    for (int j = 0; j < 128; ++j)
        acc = fmaf(G[j * 128 + i], V[j * 512 + n], acc);
    out[(size_t)b * (VSZ + SSZ) + i * 512 + n] = acc;
}

// ---------------------------------------------------------------------------
// Kernel 3: sn = Ginv @ S.  M=128 (full), N tile = 128 columns, K tiled by 16.
// 256 threads: 16 i-groups x 16 x-groups, 8x8 register tile each.
// LDS: GT tile 16x128 (8 KB) + S tile 16x128 (8 KB) -> high occupancy.
// S read exactly once (402 MB), C written once (402 MB).
// ---------------------------------------------------------------------------
__global__ __launch_bounds__(256)
void sgemm_inv(const float* __restrict__ s0, const float* __restrict__ s1,
               const float* __restrict__ s2, const float* __restrict__ ginvT,
               float* __restrict__ out) {
    const int b  = blockIdx.y;
    const float* S = (b == 0) ? s0 : ((b == 1) ? s1 : s2);
    const int xb = blockIdx.x;

    __shared__ float GTt[16 * 128];
    __shared__ float SL[16 * 128];

    const int tx = threadIdx.x & 15;       // x-group
    const int ty = threadIdx.x >> 4;       // i-group
    const int il = ty * 8;                 // local i base (i == il, M=128 full)

    const int srow0 = threadIdx.x >> 5;    // staging row 0..7
    const int c4    = threadIdx.x & 31;    // staging float4 column 0..31

    const float* Sb  = S + xb * 128;
    const float* Gb  = ginvT + b * 16384;

    float acc[8][8];
    #pragma unroll
    for (int ii = 0; ii < 8; ++ii)
        #pragma unroll
        for (int xx = 0; xx < 8; ++xx) acc[ii][xx] = 0.0f;

    for (int jt = 0; jt < 8; ++jt) {
        // stage S tile [16][128] and GT tile [16][128]
        #pragma unroll
        for (int sr = 0; sr < 2; ++sr) {
            const int row = srow0 + sr * 8;
            *(float4*)(SL  + row * 128 + c4 * 4) =
                *(const float4*)(Sb + (size_t)(jt * 16 + row) * NX + c4 * 4);
            *(float4*)(GTt + row * 128 + c4 * 4) =
                *(const float4*)(Gb + (jt * 16 + row) * 128 + c4 * 4);
        }
        __syncthreads();
        #pragma unroll 2
        for (int j = 0; j < 16; ++j) {
            const float* gr = GTt + j * 128 + il;
            float4 A0 = *(const float4*)(gr);
            float4 A1 = *(const float4*)(gr + 4);
            const float* br = SL + j * 128 + tx * 8;
            float4 B0 = *(const float4*)(br);
            float4 B1 = *(const float4*)(br + 4);
            float av[8] = {A0.x, A0.y, A0.z, A0.w, A1.x, A1.y, A1.z, A1.w};
            float bv[8] = {B0.x, B0.y, B0.z, B0.w, B1.x, B1.y, B1.z, B1.w};
            #pragma unroll
            for (int ii = 0; ii < 8; ++ii)
                #pragma unroll
                for (int xx = 0; xx < 8; ++xx)
                    acc[ii][xx] = fmaf(av[ii], bv[xx], acc[ii][xx]);
        }
        __syncthreads();
    }

    // epilogue: C[i][x], coalesced float4 stores
    float* O = out + (size_t)b * (VSZ + SSZ) + VSZ + (size_t)xb * 128 + tx * 8;
    #pragma unroll
    for (int ii = 0; ii < 8; ++ii) {
        float4 o0 = make_float4(acc[ii][0], acc[ii][1], acc[ii][2], acc[ii][3]);
        float4 o1 = make_float4(acc[ii][4], acc[ii][5], acc[ii][6], acc[ii][7]);
        *(float4*)(O + (size_t)(il + ii) * NX)     = o0;
        *(float4*)(O + (size_t)(il + ii) * NX + 4) = o1;
    }
}

// ---------------------------------------------------------------------------
extern "C" void kernel_launch(void* const* d_in, const int* in_sizes, int n_in,
                              void* d_out, int out_size, void* d_ws, size_t ws_size,
                              hipStream_t stream) {
    const float* g0 = (const float*)d_in[0];
    const float* g1 = (const float*)d_in[1];
    const float* g2 = (const float*)d_in[2];
    const float* v0 = (const float*)d_in[3];
    const float* v1 = (const float*)d_in[4];
    const float* v2 = (const float*)d_in[5];
    const float* s0 = (const float*)d_in[6];
    const float* s1 = (const float*)d_in[7];
    const float* s2 = (const float*)d_in[8];
    float* out   = (float*)d_out;
    float* ginvT = (float*)d_ws;   // 3 * 128*128 floats = 192 KiB scratch

    invert_gj<<<3, 1024, 0, stream>>>(g0, g1, g2, ginvT);
    vt_kernel<<<dim3(256, 3), 256, 0, stream>>>(g0, g1, g2, v0, v1, v2, out);
    sgemm_inv<<<dim3(2048, 3), 256, 0, stream>>>(s0, s1, s2, ginvT, out);
}